// Round 9
// baseline (1288.824 us; speedup 1.0000x reference)
//
#include <hip/hip_runtime.h>
#include <hip/hip_bf16.h>

namespace {

constexpr int kB = 512, kN = 32, kHS = 512, kHS2 = 1024, kHS3 = 1536;
constexpr int kGS = 1024, kNZ = 56, kTE = 3;

typedef __attribute__((ext_vector_type(8))) short bf16x8;
typedef __attribute__((ext_vector_type(4))) float f32x4;

__device__ inline ushort f2bf(float f) {
    union { float f; unsigned u; } v; v.f = f;
    unsigned r = v.u + 0x7fffu + ((v.u >> 16) & 1u);
    return (ushort)(r >> 16);
}
__device__ inline float bf2f(ushort b) {
    union { unsigned u; float f; } v; v.u = ((unsigned)b) << 16;
    return v.f;
}

// ================= one-time weight prep =====================================
// WnsT (2048 x 512): rows 0-1023 = Wn^T, rows 1024-2047 = Ws^T
__global__ __launch_bounds__(256) void wnst_kernel(const float* __restrict__ fe_w,
    ushort* __restrict__ out)
{
    int idx = blockIdx.x * 256 + threadIdx.x;  // < 2048*512
    int n = idx >> 9, k = idx & 511;
    float v = (n < kHS2) ? fe_w[(size_t)k * kHS2 + n]
                         : fe_w[(size_t)(kHS + 1 + k) * kHS2 + (n - kHS2)];
    out[idx] = f2bf(v);
}

// gateMapT (2048 x 512): rows 0-1023 = gate_w^T, 1024-2047 = mapper_w^T
__global__ __launch_bounds__(256) void gatemap_kernel(const float* __restrict__ gw,
    const float* __restrict__ mw, ushort* __restrict__ out)
{
    int idx = blockIdx.x * 256 + threadIdx.x;  // < 2048*512
    int n = idx >> 9, k = idx & 511;
    float v = (n < kGS) ? gw[(size_t)k * kGS + n] : mw[(size_t)k * kGS + (n - kGS)];
    out[idx] = f2bf(v);
}

// catRZN[t] (1536 x 1536): row n, col k:
//  k<1024: wih[t][n][k];  k>=1024: n<1024 ? whh[t][n][k-1024] : 0
__global__ __launch_bounds__(256) void catrzn_kernel(const float* __restrict__ wih,
    const float* __restrict__ whh, ushort* __restrict__ out)
{
    int k = blockIdx.x * 256 + threadIdx.x;  // <1536
    int n = blockIdx.y, t = blockIdx.z;
    float v;
    if (k < kHS2)       v = wih[((size_t)t * kHS3 + n) * kHS2 + k];
    else if (n < kHS2)  v = whh[((size_t)t * kHS3 + n) * kHS + (k - kHS2)];
    else                v = 0.f;
    out[((size_t)t * kHS3 + n) * kHS3 + k] = f2bf(v);
}

// whhN[t] (512 x 512) = whh[t][1024+n][k]
__global__ __launch_bounds__(256) void whhn_kernel(const float* __restrict__ whh,
    ushort* __restrict__ out)
{
    int k = blockIdx.x * 256 + threadIdx.x;
    int n = blockIdx.y, t = blockIdx.z;
    out[((size_t)t * kHS + n) * kHS + k] =
        f2bf(whh[((size_t)t * kHS3 + kHS2 + n) * kHS + k]);
}

// ================= small precompute =========================================
__global__ __launch_bounds__(256) void deg_kernel(const float* __restrict__ adj,
    float* __restrict__ deg)
{
    int idx = blockIdx.x * 256 + threadIdx.x;  // < kB*kN
    int b = idx >> 5, v = idx & 31;
    const float* p = adj + (size_t)b * kN * kN + v;
    float s = 0.f;
    #pragma unroll
    for (int u = 0; u < kN; ++u) s += p[u * kN];
    deg[idx] = s;
}

__global__ void haspred_kernel(const float* __restrict__ deg, int* __restrict__ hp)
{
    int v = threadIdx.x;  // 32
    float s = 0.f;
    for (int b = 0; b < kB; ++b) s += deg[b * kN + v];
    hp[v] = (s > 0.f) ? 1 : 0;
}

// biasHS (2048): [0 | we+fe_b]
__global__ void biasHS_kernel(const float* __restrict__ fe_w,
    const float* __restrict__ fe_b, float* __restrict__ o)
{
    int e = blockIdx.x * 256 + threadIdx.x;  // < 2048
    o[e] = (e < kHS2) ? 0.f
                      : fe_w[(size_t)kHS * kHS2 + (e - kHS2)] + fe_b[e - kHS2];
}

// biasGXN (t,1536): [bih_rz+bhh_rz | bih_n]
__global__ void biasGXN_kernel(const float* __restrict__ bih,
    const float* __restrict__ bhh, float* __restrict__ o)
{
    int idx = blockIdx.x * 256 + threadIdx.x;  // < kTE*1536
    int t = idx / kHS3, e = idx % kHS3;
    float v = bih[t * kHS3 + e];
    if (e < kHS2) v += bhh[t * kHS3 + e];
    o[idx] = v;
}

// biasRO (2048): [gate_b | 0]
__global__ void biasRO_kernel(const float* __restrict__ gb, float* __restrict__ o)
{
    int e = blockIdx.x * 256 + threadIdx.x;
    o[e] = (e < kGS) ? gb[e] : 0.f;
}

// ---------------- H init: AvH[m, 1024+h] = bf16(finit_w[nt[m],h]+finit_b[h]) -
__global__ __launch_bounds__(256) void hinit_kernel(const int* __restrict__ nt,
    const float* __restrict__ finit_w, const float* __restrict__ finit_b,
    ushort* __restrict__ AvH)
{
    int idx = blockIdx.x * 256 + threadIdx.x;  // < MC*kHS
    int m = idx >> 9;
    int h = idx & 511;
    int t = nt[m];
    AvH[(size_t)m * kHS3 + kHS2 + h] = f2bf(finit_w[t * kHS + h] + finit_b[h]);
}

// ================= MFMA bf16 GEMM v2: C = A(bf16) @ B(bf16)^T (+bias) =======
// A: (M,K) bf16, row stride lda. B: (N,K) bf16 dense. C: (M,N) CT dense.
// BM=128, BN=256, BK=32, 256 thr (4 waves 2Mx2N), wave-tile 64x128.
// A staged in LDS (3 bufs x 8KB, XOR slot swizzle, pre-swizzled global src).
// B loaded DIRECTLY global->VGPR (8 frags/wave), double-banked, L2-served via
// by-fastest XCD chunk swizzle (each XCD's L2 holds <=2 B panels).
// Counted vmcnt: per iter issues Bpre(t+1)[8] then AstageLDS(t+2)[2];
// entry(t) needs A(t): 10 newer ops -> vmcnt(10); MFMA(t) needs Bpre(t):
// 12 newer -> vmcnt(12). Tail peeled with exact drains. One barrier/tile.
template<typename CT>
__global__ __launch_bounds__(256, 2) void gemm_bf16(const ushort* __restrict__ A,
    const ushort* __restrict__ B, CT* __restrict__ C,
    const float* __restrict__ bias, int M_, int N_, int K_, int lda)
{
    __shared__ ushort As[3 * 4096];   // 3 bufs x 128x32
    const int tid = threadIdx.x;
    const int w = tid >> 6, l = tid & 63;
    const int l15 = l & 15;
    const int wm = w >> 1, wn = w & 1;

    // XCD chunk swizzle, by-fastest decode: same bx stays on one XCD
    int nwg = gridDim.x * gridDim.y;
    int bid = blockIdx.y * gridDim.x + blockIdx.x;
    int swz = (nwg & 7) ? bid : ((bid & 7) * (nwg >> 3) + (bid >> 3));
    const int by = swz % gridDim.y, bx = swz / gridDim.y;
    const int mT = by * 128, nT = bx * 256;

    const int NT = K_ >> 5;  // >= 16, even for all shapes here

    auto stageA = [&](int t) {
        int buf = t % 3, kt2 = t * 32;
        #pragma unroll
        for (int i = 0; i < 2; ++i) {
            int idx = tid + i * 256;
            int row = idx >> 2, sl = idx & 3;
            int gs = sl ^ ((row >> 1) & 3);
            const ushort* g = A + (size_t)(mT + row) * lda + kt2 + gs * 8;
            __builtin_amdgcn_global_load_lds(
                (const __attribute__((address_space(1))) void*)g,
                (__attribute__((address_space(3))) void*)(As + buf * 4096 + idx * 8),
                16, 0, 0);
        }
    };

    // B per-lane pointers: frag j covers rows nT + wn*128 + j*16 .. +15
    const ushort* bp0 = B + (size_t)(nT + wn * 128 +  0 + l15) * K_ + (l >> 4) * 8;
    const ushort* bp1 = B + (size_t)(nT + wn * 128 + 16 + l15) * K_ + (l >> 4) * 8;
    const ushort* bp2 = B + (size_t)(nT + wn * 128 + 32 + l15) * K_ + (l >> 4) * 8;
    const ushort* bp3 = B + (size_t)(nT + wn * 128 + 48 + l15) * K_ + (l >> 4) * 8;
    const ushort* bp4 = B + (size_t)(nT + wn * 128 + 64 + l15) * K_ + (l >> 4) * 8;
    const ushort* bp5 = B + (size_t)(nT + wn * 128 + 80 + l15) * K_ + (l >> 4) * 8;
    const ushort* bp6 = B + (size_t)(nT + wn * 128 + 96 + l15) * K_ + (l >> 4) * 8;
    const ushort* bp7 = B + (size_t)(nT + wn * 128 + 112 + l15) * K_ + (l >> 4) * 8;

    bf16x8 bA[8], bB[8];
    #define LOAD_BANK(bank)                                            \
        do {                                                           \
            bank[0] = *reinterpret_cast<const bf16x8*>(bp0); bp0 += 32;\
            bank[1] = *reinterpret_cast<const bf16x8*>(bp1); bp1 += 32;\
            bank[2] = *reinterpret_cast<const bf16x8*>(bp2); bp2 += 32;\
            bank[3] = *reinterpret_cast<const bf16x8*>(bp3); bp3 += 32;\
            bank[4] = *reinterpret_cast<const bf16x8*>(bp4); bp4 += 32;\
            bank[5] = *reinterpret_cast<const bf16x8*>(bp5); bp5 += 32;\
            bank[6] = *reinterpret_cast<const bf16x8*>(bp6); bp6 += 32;\
            bank[7] = *reinterpret_cast<const bf16x8*>(bp7); bp7 += 32;\
        } while (0)

    f32x4 acc[4][8] = {};
    const int swd = ((l >> 4) ^ (l15 >> 1)) & 3;   // swizzled read slot

    // prologue: A tiles 0,1 to LDS; B tile 0 to bank A
    stageA(0);
    stageA(1);
    LOAD_BANK(bA);

    bf16x8 af[4];
    #define DS_AF(t)                                                         \
        do {                                                                 \
            const ushort* Ab_ = As + ((t) % 3) * 4096;                       \
            _Pragma("unroll")                                                \
            for (int mi = 0; mi < 4; ++mi)                                   \
                af[mi] = *reinterpret_cast<const bf16x8*>(                   \
                    &Ab_[(wm * 64 + mi * 16 + l15) * 32 + swd * 8]);         \
        } while (0)

    #define MFMA_ALL(bank)                                                   \
        do {                                                                 \
            __builtin_amdgcn_s_setprio(1);                                   \
            _Pragma("unroll")                                                \
            for (int mi = 0; mi < 4; ++mi)                                   \
                _Pragma("unroll")                                            \
                for (int nj = 0; nj < 8; ++nj)                               \
                    acc[mi][nj] = __builtin_amdgcn_mfma_f32_16x16x32_bf16(   \
                        af[mi], bank[nj], acc[mi][nj], 0, 0, 0);             \
            __builtin_amdgcn_s_setprio(0);                                   \
        } while (0)

    // main loop: pairs, t+2 < NT guaranteed inside
    int t = 0;
    for (; t + 2 < NT - 1; t += 2) {
        // even iter: use bank A, load bank B
        asm volatile("s_waitcnt vmcnt(10)" ::: "memory");
        __builtin_amdgcn_s_barrier();
        DS_AF(t);
        LOAD_BANK(bB);
        stageA(t + 2);
        asm volatile("s_waitcnt vmcnt(12) lgkmcnt(0)" ::: "memory");
        __builtin_amdgcn_sched_barrier(0);
        MFMA_ALL(bA);

        // odd iter: use bank B, load bank A
        asm volatile("s_waitcnt vmcnt(10)" ::: "memory");
        __builtin_amdgcn_s_barrier();
        DS_AF(t + 1);
        LOAD_BANK(bA);
        stageA(t + 3);
        asm volatile("s_waitcnt vmcnt(12) lgkmcnt(0)" ::: "memory");
        __builtin_amdgcn_sched_barrier(0);
        MFMA_ALL(bB);
    }
    // t == NT-2 here (NT even). Tail iter 1: use bank A, load bank B (last).
    asm volatile("s_waitcnt vmcnt(10)" ::: "memory");
    __builtin_amdgcn_s_barrier();
    DS_AF(NT - 2);
    LOAD_BANK(bB);              // Bpre(NT-1)
    asm volatile("s_waitcnt vmcnt(10) lgkmcnt(0)" ::: "memory");
    __builtin_amdgcn_sched_barrier(0);
    MFMA_ALL(bA);
    // Tail iter 2: use bank B, nothing to load.
    asm volatile("s_waitcnt vmcnt(8)" ::: "memory");
    __builtin_amdgcn_s_barrier();
    DS_AF(NT - 1);
    asm volatile("s_waitcnt vmcnt(0) lgkmcnt(0)" ::: "memory");
    __builtin_amdgcn_sched_barrier(0);
    MFMA_ALL(bB);

    #undef LOAD_BANK
    #undef DS_AF
    #undef MFMA_ALL

    // epilogue: C/D layout col=lane&15, row=(lane>>4)*4+q
    const int row0 = (l >> 4) * 4;
    #pragma unroll
    for (int nj = 0; nj < 8; ++nj) {
        int col = nT + wn * 128 + nj * 16 + l15;
        float bv = bias ? bias[col] : 0.f;
        #pragma unroll
        for (int mi = 0; mi < 4; ++mi) {
            #pragma unroll
            for (int q = 0; q < 4; ++q) {
                int row = mT + wm * 64 + mi * 16 + row0 + q;
                float val = acc[mi][nj][q] + bv;
                if constexpr (sizeof(CT) == 2)
                    C[(size_t)row * N_ + col] = (CT)f2bf(val);
                else
                    C[(size_t)row * N_ + col] = (CT)val;
            }
        }
    }
}

template<typename CT>
void launch_gemm(const ushort* A, int lda, const ushort* B, CT* C,
                 const float* bias, int M_, int N_, int K_, hipStream_t stream)
{
    dim3 grid(N_ / 256, M_ / 128);
    gemm_bf16<CT><<<grid, 256, 0, stream>>>(A, B, C, bias, M_, N_, K_, lda);
}

// ---- Av[b,v,e] = sum_u adj[b,u,v]*Hu[b,u,e] + deg[b,v]*St[b,v,e] -----------
// HuSt bf16 (M,2048): Hu = cols 0-1023, St = cols 1024-2047. Out: AvH bf16.
__global__ __launch_bounds__(256) void av_kernel(const float* __restrict__ adj,
    const ushort* __restrict__ HuSt, const float* __restrict__ deg,
    ushort* __restrict__ AvH)
{
    __shared__ float adjs[kN * kN];
    __shared__ float degs[kN];
    int b = blockIdx.y;
    int e = blockIdx.x * 256 + threadIdx.x;  // < 1024
    {
        const float4* src = reinterpret_cast<const float4*>(adj + (size_t)b * kN * kN);
        float4 v = src[threadIdx.x];
        *reinterpret_cast<float4*>(&adjs[threadIdx.x * 4]) = v;
        if (threadIdx.x < kN) degs[threadIdx.x] = deg[b * kN + threadIdx.x];
    }
    __syncthreads();

    const size_t rbase = (size_t)b * kN * 2048 + e;
    float acc[kN];
    #pragma unroll
    for (int v = 0; v < kN; ++v)
        acc[v] = degs[v] * bf2f(HuSt[rbase + (size_t)v * 2048 + kHS2]);
    for (int u = 0; u < kN; ++u) {
        float hu = bf2f(HuSt[rbase + (size_t)u * 2048]);
        #pragma unroll
        for (int v4 = 0; v4 < kN / 4; ++v4) {
            float4 a = *reinterpret_cast<const float4*>(&adjs[u * kN + v4 * 4]);
            acc[v4 * 4 + 0] = fmaf(a.x, hu, acc[v4 * 4 + 0]);
            acc[v4 * 4 + 1] = fmaf(a.y, hu, acc[v4 * 4 + 1]);
            acc[v4 * 4 + 2] = fmaf(a.z, hu, acc[v4 * 4 + 2]);
            acc[v4 * 4 + 3] = fmaf(a.w, hu, acc[v4 * 4 + 3]);
        }
    }
    const size_t obase = (size_t)b * kN * kHS3 + e;
    #pragma unroll
    for (int v = 0; v < kN; ++v) AvH[obase + (size_t)v * kHS3] = f2bf(acc[v]);
}

// ---------------- GRU gating + has_pred select (H bf16 inside AvH) ----------
// gxzn bf16 (M,1536): r=cols[0,512), z=[512,1024), xn=[1024,1536). hn bf16 (M,512).
__global__ __launch_bounds__(256) void gru_kernel(ushort* __restrict__ AvH,
    const ushort* __restrict__ gxzn, const ushort* __restrict__ hn,
    const int* __restrict__ hp)
{
    int idx = blockIdx.x * 256 + threadIdx.x;  // < MC*kHS
    int m = idx >> 9;
    int h = idx & 511;
    size_t gb = (size_t)m * kHS3 + h;
    float rp = bf2f(gxzn[gb]);
    float zp = bf2f(gxzn[gb + kHS]);
    float xn = bf2f(gxzn[gb + 2 * kHS]);
    float hv = bf2f(hn[(size_t)m * kHS + h]);
    float r = 1.f / (1.f + __expf(-rp));
    float z = 1.f / (1.f + __expf(-zp));
    float n = tanhf(xn + r * hv);
    ushort* Hp = AvH + (size_t)m * kHS3 + kHS2 + h;
    float hold = bf2f(*Hp);
    float hnew = (1.f - z) * n + z * hold;
    *Hp = hp[m & 31] ? f2bf(hnew) : f2bf(hold);
}

// ---------------- Hg[b,g] = sum_n sigmoid(G1) * G2 --------------------------
// G12 f32 (M,2048): G1 = cols 0-1023 (incl gate_b), G2 = cols 1024-2047
__global__ __launch_bounds__(256) void hg_kernel(const float* __restrict__ G12,
    float* __restrict__ Hg)
{
    int idx = blockIdx.x * 256 + threadIdx.x;  // < CH*kGS
    int b = idx >> 10, g = idx & 1023;
    size_t base = (size_t)b * kN * 2048 + g;
    float acc = 0.f;
    #pragma unroll 8
    for (int n = 0; n < kN; ++n) {
        float s  = G12[base + (size_t)n * 2048];
        float m2 = G12[base + (size_t)n * 2048 + kGS];
        float sig = 1.f / (1.f + __expf(-s));
        acc = fmaf(sig, m2, acc);
    }
    Hg[idx] = acc;
}

// ---------------- mu/logvar heads -------------------------------------------
__global__ __launch_bounds__(64) void fc_kernel(const float* __restrict__ Hg,
    const float* __restrict__ fc1_w, const float* __restrict__ fc1_b,
    const float* __restrict__ fc2_w, const float* __restrict__ fc2_b,
    float* __restrict__ out, int b0)
{
    __shared__ float hg[kGS];
    int bl = blockIdx.x;
    for (int i = threadIdx.x; i < kGS; i += 64) hg[i] = Hg[(size_t)bl * kGS + i];
    __syncthreads();
    int j = threadIdx.x;
    if (j < kNZ) {
        float s1 = fc1_b[j], s2 = fc2_b[j];
        for (int k = 0; k < kGS; ++k) {
            float h = hg[k];
            s1 = fmaf(h, fc1_w[k * kNZ + j], s1);
            s2 = fmaf(h, fc2_w[k * kNZ + j], s2);
        }
        int bg = b0 + bl;
        out[(size_t)bg * kNZ + j] = s1;
        out[(size_t)kB * kNZ + (size_t)bg * kNZ + j] = s2;
    }
}

}  // namespace

extern "C" void kernel_launch(void* const* d_in, const int* in_sizes, int n_in,
                              void* d_out, int out_size, void* d_ws, size_t ws_size,
                              hipStream_t stream)
{
    const int*   node_types = (const int*)  d_in[0];
    const float* adj        = (const float*)d_in[1];
    const float* finit_w    = (const float*)d_in[2];
    const float* finit_b    = (const float*)d_in[3];
    const float* fe_w       = (const float*)d_in[4];
    const float* fe_b       = (const float*)d_in[5];
    const float* grue_wih   = (const float*)d_in[6];
    const float* grue_whh   = (const float*)d_in[7];
    const float* grue_bih   = (const float*)d_in[8];
    const float* grue_bhh   = (const float*)d_in[9];
    const float* gate_w     = (const float*)d_in[10];
    const float* gate_b     = (const float*)d_in[11];
    const float* mapper_w   = (const float*)d_in[12];
    const float* fc1_w      = (const float*)d_in[13];
    const float* fc1_b      = (const float*)d_in[14];
    const float* fc2_w      = (const float*)d_in[15];
    const float* fc2_b      = (const float*)d_in[16];
    float* out = (float*)d_out;

    // ---- fixed region (float units) ----
    float* W = (float*)d_ws;
    size_t o = 0;
    float*  deg     = W + o; o += (size_t)kB * kN;
    int*    hp      = (int*)(W + o); o += 64;
    float*  biasHS  = W + o; o += 2048;
    float*  biasGXN = W + o; o += kTE * kHS3;
    float*  biasRO  = W + o; o += 2048;
    float*  Hg      = W + o; o += (size_t)kB * kGS;
    ushort* WnsT    = (ushort*)(W + o); o += (size_t)2048 * kHS / 2;
    ushort* catRZN  = (ushort*)(W + o); o += (size_t)kTE * kHS3 * kHS3 / 2;
    ushort* whhN    = (ushort*)(W + o); o += (size_t)kTE * kHS * kHS / 2;
    ushort* gateMapT= (ushort*)(W + o); o += (size_t)2048 * kHS / 2;
    const size_t fixedFloats = o;

    // per-graph floats: AvH 24576 + HuSt 32768 + gxzn 24576 + hn 8192 = 90112
    const size_t perGraph = 90112;
    int CH = 512;
    while (CH > 4 &&
           (fixedFloats + (size_t)CH * perGraph) * sizeof(float) > ws_size)
        CH >>= 1;

    // ---- one-time precompute ----
    deg_kernel<<<kB * kN / 256, 256, 0, stream>>>(adj, deg);
    haspred_kernel<<<1, kN, 0, stream>>>(deg, hp);
    biasHS_kernel<<<2048 / 256, 256, 0, stream>>>(fe_w, fe_b, biasHS);
    biasGXN_kernel<<<kTE * kHS3 / 256, 256, 0, stream>>>(grue_bih, grue_bhh, biasGXN);
    biasRO_kernel<<<2048 / 256, 256, 0, stream>>>(gate_b, biasRO);
    wnst_kernel<<<2048 * kHS / 256, 256, 0, stream>>>(fe_w, WnsT);
    catrzn_kernel<<<dim3(kHS3 / 256, kHS3, kTE), 256, 0, stream>>>(grue_wih, grue_whh, catRZN);
    whhn_kernel<<<dim3(kHS / 256, kHS, kTE), 256, 0, stream>>>(grue_whh, whhN);
    gatemap_kernel<<<2048 * kHS / 256, 256, 0, stream>>>(gate_w, mapper_w, gateMapT);

    for (int b0 = 0; b0 < kB; b0 += CH) {
        const int MC = CH * kN;  // rows (multiple of 128)
        ushort* AvH  = (ushort*)(W + fixedFloats);        // MC x 1536 bf16
        ushort* HuSt = AvH  + (size_t)MC * kHS3;          // MC x 2048 bf16
        ushort* gxzn = HuSt + (size_t)MC * 2048;          // MC x 1536 bf16
        ushort* hnb  = gxzn + (size_t)MC * kHS3;          // MC x 512  bf16
        float*  G12  = (float*)HuSt;                      // MC x 2048 f32 (overlay)
        ushort* Hc   = AvH + kHS2;                        // H view, lda 1536

        hinit_kernel<<<MC * kHS / 256, 256, 0, stream>>>(
            node_types + (size_t)b0 * kN, finit_w, finit_b, AvH);

        for (int t = 0; t < kTE; ++t) {
            // HuSt = H @ WnsT^T + [0 | we+fe_b]   (MC x 2048, bf16)
            launch_gemm<ushort>(Hc, kHS3, WnsT, HuSt, biasHS, MC, 2048, kHS, stream);
            // Av -> AvH[:, 0:1024]
            {
                dim3 g(kHS2 / 256, CH);
                av_kernel<<<g, 256, 0, stream>>>(
                    adj + (size_t)b0 * kN * kN, HuSt, deg + (size_t)b0 * kN, AvH);
            }
            // gxzn = [Av|H] @ catRZN[t]^T + biasGXN[t]   (MC x 1536, K=1536)
            launch_gemm<ushort>(AvH, kHS3, catRZN + (size_t)t * kHS3 * kHS3, gxzn,
                                biasGXN + t * kHS3, MC, kHS3, kHS3, stream);
            // hn = H @ whhN[t]^T + bhh_n   (MC x 512)
            launch_gemm<ushort>(Hc, kHS3, whhN + (size_t)t * kHS * kHS, hnb,
                                grue_bhh + t * kHS3 + kHS2, MC, kHS, kHS, stream);
            // GRU gating (H in place)
            gru_kernel<<<MC * kHS / 256, 256, 0, stream>>>(AvH, gxzn, hnb, hp);
        }

        // readout: G12 = H @ [gate|mapper]^T + [gate_b|0]  (MC x 2048, f32)
        launch_gemm<float>(Hc, kHS3, gateMapT, G12, biasRO, MC, 2048, kHS, stream);
        hg_kernel<<<CH * kGS / 256, 256, 0, stream>>>(G12, Hg);
        fc_kernel<<<CH, 64, 0, stream>>>(Hg, fc1_w, fc1_b, fc2_w, fc2_b, out, b0);
    }
}

// Round 11
// 914.365 us; speedup vs baseline: 1.4095x; 1.4095x over previous
//
#include <hip/hip_runtime.h>
#include <hip/hip_bf16.h>

namespace {

constexpr int kB = 512, kN = 32, kHS = 512, kHS2 = 1024, kHS3 = 1536;
constexpr int kGS = 1024, kNZ = 56, kTE = 3;

typedef __attribute__((ext_vector_type(8))) short bf16x8;
typedef __attribute__((ext_vector_type(4))) float f32x4;

__device__ inline ushort f2bf(float f) {
    union { float f; unsigned u; } v; v.f = f;
    unsigned r = v.u + 0x7fffu + ((v.u >> 16) & 1u);
    return (ushort)(r >> 16);
}
__device__ inline float bf2f(ushort b) {
    union { unsigned u; float f; } v; v.u = ((unsigned)b) << 16;
    return v.f;
}

// ================= one-time weight prep =====================================
// WnsT (2048 x 512): rows 0-1023 = Wn^T, rows 1024-2047 = Ws^T
__global__ __launch_bounds__(256) void wnst_kernel(const float* __restrict__ fe_w,
    ushort* __restrict__ out)
{
    int idx = blockIdx.x * 256 + threadIdx.x;  // < 2048*512
    int n = idx >> 9, k = idx & 511;
    float v = (n < kHS2) ? fe_w[(size_t)k * kHS2 + n]
                         : fe_w[(size_t)(kHS + 1 + k) * kHS2 + (n - kHS2)];
    out[idx] = f2bf(v);
}

// gateMapT (2048 x 512): rows 0-1023 = gate_w^T, 1024-2047 = mapper_w^T
__global__ __launch_bounds__(256) void gatemap_kernel(const float* __restrict__ gw,
    const float* __restrict__ mw, ushort* __restrict__ out)
{
    int idx = blockIdx.x * 256 + threadIdx.x;  // < 2048*512
    int n = idx >> 9, k = idx & 511;
    float v = (n < kGS) ? gw[(size_t)k * kGS + n] : mw[(size_t)k * kGS + (n - kGS)];
    out[idx] = f2bf(v);
}

// catRZNH[t] (2048 x 1536): row n, col k:
//  n<1536:  k<1024 ? wih[t][n][k] : (n<1024 ? whh[t][n][k-1024] : 0)
//  n>=1536: k<1024 ? 0 : whh[t][1024+(n-1536)][k-1024]     (the hn block)
__global__ __launch_bounds__(256) void catrznh_kernel(const float* __restrict__ wih,
    const float* __restrict__ whh, ushort* __restrict__ out)
{
    int k = blockIdx.x * 256 + threadIdx.x;  // <1536
    int n = blockIdx.y, t = blockIdx.z;
    float v;
    if (n < kHS3) {
        if (k < kHS2)       v = wih[((size_t)t * kHS3 + n) * kHS2 + k];
        else if (n < kHS2)  v = whh[((size_t)t * kHS3 + n) * kHS + (k - kHS2)];
        else                v = 0.f;
    } else {
        v = (k >= kHS2)
          ? whh[((size_t)t * kHS3 + kHS2 + (n - kHS3)) * kHS + (k - kHS2)]
          : 0.f;
    }
    out[((size_t)t * 2048 + n) * kHS3 + k] = f2bf(v);
}

// ================= small precompute =========================================
__global__ __launch_bounds__(256) void deg_kernel(const float* __restrict__ adj,
    float* __restrict__ deg)
{
    int idx = blockIdx.x * 256 + threadIdx.x;  // < kB*kN
    int b = idx >> 5, v = idx & 31;
    const float* p = adj + (size_t)b * kN * kN + v;
    float s = 0.f;
    #pragma unroll
    for (int u = 0; u < kN; ++u) s += p[u * kN];
    deg[idx] = s;
}

__global__ void haspred_kernel(const float* __restrict__ deg, int* __restrict__ hp)
{
    int v = threadIdx.x;  // 32
    float s = 0.f;
    for (int b = 0; b < kB; ++b) s += deg[b * kN + v];
    hp[v] = (s > 0.f) ? 1 : 0;
}

// biasHS (2048): [0 | we+fe_b]
__global__ void biasHS_kernel(const float* __restrict__ fe_w,
    const float* __restrict__ fe_b, float* __restrict__ o)
{
    int e = blockIdx.x * 256 + threadIdx.x;  // < 2048
    o[e] = (e < kHS2) ? 0.f
                      : fe_w[(size_t)kHS * kHS2 + (e - kHS2)] + fe_b[e - kHS2];
}

// biasGXNH (t,2048): [bih_rz+bhh_rz | bih_n | bhh_n]
__global__ void biasGXNH_kernel(const float* __restrict__ bih,
    const float* __restrict__ bhh, float* __restrict__ o)
{
    int idx = blockIdx.x * 256 + threadIdx.x;  // < kTE*2048
    int t = idx >> 11, e = idx & 2047;
    float v;
    if (e < kHS2)      v = bih[t * kHS3 + e] + bhh[t * kHS3 + e];
    else if (e < kHS3) v = bih[t * kHS3 + e];
    else               v = bhh[t * kHS3 + (e - 512)];
    o[idx] = v;
}

// biasRO (2048): [gate_b | 0]
__global__ void biasRO_kernel(const float* __restrict__ gb, float* __restrict__ o)
{
    int e = blockIdx.x * 256 + threadIdx.x;
    o[e] = (e < kGS) ? gb[e] : 0.f;
}

// ---------------- H init: AvH[m, 1024+h] = bf16(finit_w[nt[m],h]+finit_b[h]) -
__global__ __launch_bounds__(256) void hinit_kernel(const int* __restrict__ nt,
    const float* __restrict__ finit_w, const float* __restrict__ finit_b,
    ushort* __restrict__ AvH)
{
    int idx = blockIdx.x * 256 + threadIdx.x;  // < MC*kHS
    int m = idx >> 9;
    int h = idx & 511;
    int t = nt[m];
    AvH[(size_t)m * kHS3 + kHS2 + h] = f2bf(finit_w[t * kHS + h] + finit_b[h]);
}

// ================= MFMA bf16 GEMM: C = A(bf16) @ B(bf16)^T (+bias) ==========
// A: (M,K) bf16, row stride lda. B: (N,K) bf16 dense. C: (M,N) CT dense.
// 256x256 tile, BK=32, 512 thr (8 waves 2Mx4N), wave-tile 128x64 (8x4 frags).
// 2-buffer LDS (64 KB). Per K-tile phases:
//   entry: vmcnt(4) counted (tile t landed; t+1's 4 loads may fly) + barrier
//   ph0: ds_read A-lo(4)+B(4) -> 16 MFMA (mi0-3 x nj0-3)
//   ph1: ds_read A-hi(4); lgkm0; BARRIER (all reads of buf p done)
//        stageA(t+2) || 8 MFMA (mi4-7 x nj0-1); stageB(t+2) || 8 MFMA (nj2-3)
// Swizzle = R4's HW-verified pair: stage gs = sl ^ ((row>>1)&3); read
// ps = (khi ^ (l15>>1)) & 3. setprio around MFMA clusters.
template<typename CT>
__global__ __launch_bounds__(512, 2) void gemm_bf16(const ushort* __restrict__ A,
    const ushort* __restrict__ B, CT* __restrict__ C,
    const float* __restrict__ bias, int M_, int N_, int K_, int lda)
{
    __shared__ ushort smem[32768];  // A: [2][8192] ush, B: 16384 + [2][8192]
    const int tid = threadIdx.x;
    const int w = tid >> 6, l = tid & 63;
    const int l15 = l & 15;
    const int wm = w >> 2, wn = w & 3;
    const int khi = l >> 4;

    // XCD-aware bijective swizzle (only when nwg % 8 == 0)
    int nwg = gridDim.x * gridDim.y;
    int bid = blockIdx.y * gridDim.x + blockIdx.x;
    int swz = (nwg & 7) ? bid : ((bid & 7) * (nwg >> 3) + (bid >> 3));
    const int bx = swz % gridDim.x, by = swz / gridDim.x;
    const int mT = by * 256, nT = bx * 256;

    const int NT = K_ >> 5;  // BK=32 tiles; >= 16 for all shapes here

    auto stageA = [&](int t) {
        int p = t & 1, kt = t * 32;
        #pragma unroll
        for (int r = 0; r < 2; ++r) {
            int idx = r * 512 + tid;          // 0..1023 (256 rows x 4 slots)
            int row = idx >> 2, sl = idx & 3;
            int gs = sl ^ ((row >> 1) & 3);
            const ushort* g = A + (size_t)(mT + row) * lda + kt + gs * 8;
            __builtin_amdgcn_global_load_lds(
                (const __attribute__((address_space(1))) void*)g,
                (__attribute__((address_space(3))) void*)(smem + p * 8192 + idx * 8),
                16, 0, 0);
        }
    };
    auto stageB = [&](int t) {
        int p = t & 1, kt = t * 32;
        #pragma unroll
        for (int r = 0; r < 2; ++r) {
            int idx = r * 512 + tid;
            int row = idx >> 2, sl = idx & 3;
            int gs = sl ^ ((row >> 1) & 3);
            const ushort* g = B + (size_t)(nT + row) * K_ + kt + gs * 8;
            __builtin_amdgcn_global_load_lds(
                (const __attribute__((address_space(1))) void*)g,
                (__attribute__((address_space(3))) void*)(smem + 16384 + p * 8192 + idx * 8),
                16, 0, 0);
        }
    };

    f32x4 acc[8][4] = {};
    bf16x8 af[4], bfr[4];
    const int ps = (khi ^ (l15 >> 1)) & 3;   // swizzled read slot

    auto dsA = [&](int p, int mb) {
        const ushort* base = smem + p * 8192;
        #pragma unroll
        for (int mi = 0; mi < 4; ++mi) {
            int ra = wm * 128 + (mb + mi) * 16 + l15;
            af[mi] = *reinterpret_cast<const bf16x8*>(base + ra * 32 + ps * 8);
        }
    };
    auto dsB = [&](int p) {
        const ushort* base = smem + 16384 + p * 8192;
        #pragma unroll
        for (int nj = 0; nj < 4; ++nj) {
            int rb = wn * 64 + nj * 16 + l15;
            bfr[nj] = *reinterpret_cast<const bf16x8*>(base + rb * 32 + ps * 8);
        }
    };

    // prologue: stage tiles 0 and 1 (8 loads/thread)
    stageA(0); stageB(0);
    stageA(1); stageB(1);

    for (int t = 0; t < NT; ++t) {
        const int p = t & 1;
        if (t + 1 < NT) asm volatile("s_waitcnt vmcnt(4)" ::: "memory");
        else            asm volatile("s_waitcnt vmcnt(0)" ::: "memory");
        __builtin_amdgcn_s_barrier();

        // ---- phase 0: A-lo + B reads, 16 MFMA ----
        dsA(p, 0);
        dsB(p);
        asm volatile("s_waitcnt lgkmcnt(0)" ::: "memory");
        __builtin_amdgcn_sched_barrier(0);
        __builtin_amdgcn_s_setprio(1);
        #pragma unroll
        for (int mi = 0; mi < 4; ++mi)
            #pragma unroll
            for (int nj = 0; nj < 4; ++nj)
                acc[mi][nj] = __builtin_amdgcn_mfma_f32_16x16x32_bf16(
                    af[mi], bfr[nj], acc[mi][nj], 0, 0, 0);
        __builtin_amdgcn_s_setprio(0);

        // ---- phase 1: A-hi reads, then all-reads barrier ----
        dsA(p, 4);
        asm volatile("s_waitcnt lgkmcnt(0)" ::: "memory");
        __builtin_amdgcn_sched_barrier(0);
        __builtin_amdgcn_s_barrier();   // every wave done reading buf p

        const bool st = (t + 2 < NT);
        if (st) stageA(t + 2);          // overwrite buf p (now dead)
        __builtin_amdgcn_s_setprio(1);
        #pragma unroll
        for (int mi = 0; mi < 4; ++mi)
            #pragma unroll
            for (int nj = 0; nj < 2; ++nj)
                acc[4 + mi][nj] = __builtin_amdgcn_mfma_f32_16x16x32_bf16(
                    af[mi], bfr[nj], acc[4 + mi][nj], 0, 0, 0);
        __builtin_amdgcn_s_setprio(0);
        if (st) stageB(t + 2);
        __builtin_amdgcn_s_setprio(1);
        #pragma unroll
        for (int mi = 0; mi < 4; ++mi)
            #pragma unroll
            for (int nj = 2; nj < 4; ++nj)
                acc[4 + mi][nj] = __builtin_amdgcn_mfma_f32_16x16x32_bf16(
                    af[mi], bfr[nj], acc[4 + mi][nj], 0, 0, 0);
        __builtin_amdgcn_s_setprio(0);
    }

    // epilogue: C/D layout col=lane&15, row=(lane>>4)*4+q
    const int row0 = khi * 4;
    #pragma unroll
    for (int nj = 0; nj < 4; ++nj) {
        int col = nT + wn * 64 + nj * 16 + l15;
        float bv = bias ? bias[col] : 0.f;
        #pragma unroll
        for (int mi = 0; mi < 8; ++mi) {
            #pragma unroll
            for (int q = 0; q < 4; ++q) {
                int row = mT + wm * 128 + mi * 16 + row0 + q;
                float val = acc[mi][nj][q] + bv;
                if constexpr (sizeof(CT) == 2)
                    C[(size_t)row * N_ + col] = (CT)f2bf(val);
                else
                    C[(size_t)row * N_ + col] = (CT)val;
            }
        }
    }
}

template<typename CT>
void launch_gemm(const ushort* A, int lda, const ushort* B, CT* C,
                 const float* bias, int M_, int N_, int K_, hipStream_t stream)
{
    dim3 grid(N_ / 256, M_ / 256);
    gemm_bf16<CT><<<grid, 512, 0, stream>>>(A, B, C, bias, M_, N_, K_, lda);
}

// ---- Av[b,v,e] = sum_u adj[b,u,v]*Hu[b,u,e] + deg[b,v]*St[b,v,e] -----------
// HuSt bf16 (M,2048): Hu = cols 0-1023, St = cols 1024-2047. Out: AvH bf16.
__global__ __launch_bounds__(256) void av_kernel(const float* __restrict__ adj,
    const ushort* __restrict__ HuSt, const float* __restrict__ deg,
    ushort* __restrict__ AvH)
{
    __shared__ float adjs[kN * kN];
    __shared__ float degs[kN];
    int b = blockIdx.y;
    int e = blockIdx.x * 256 + threadIdx.x;  // < 1024
    {
        const float4* src = reinterpret_cast<const float4*>(adj + (size_t)b * kN * kN);
        float4 v = src[threadIdx.x];
        *reinterpret_cast<float4*>(&adjs[threadIdx.x * 4]) = v;
        if (threadIdx.x < kN) degs[threadIdx.x] = deg[b * kN + threadIdx.x];
    }
    __syncthreads();

    const size_t rbase = (size_t)b * kN * 2048 + e;
    float acc[kN];
    #pragma unroll
    for (int v = 0; v < kN; ++v)
        acc[v] = degs[v] * bf2f(HuSt[rbase + (size_t)v * 2048 + kHS2]);
    for (int u = 0; u < kN; ++u) {
        float hu = bf2f(HuSt[rbase + (size_t)u * 2048]);
        #pragma unroll
        for (int v4 = 0; v4 < kN / 4; ++v4) {
            float4 a = *reinterpret_cast<const float4*>(&adjs[u * kN + v4 * 4]);
            acc[v4 * 4 + 0] = fmaf(a.x, hu, acc[v4 * 4 + 0]);
            acc[v4 * 4 + 1] = fmaf(a.y, hu, acc[v4 * 4 + 1]);
            acc[v4 * 4 + 2] = fmaf(a.z, hu, acc[v4 * 4 + 2]);
            acc[v4 * 4 + 3] = fmaf(a.w, hu, acc[v4 * 4 + 3]);
        }
    }
    const size_t obase = (size_t)b * kN * kHS3 + e;
    #pragma unroll
    for (int v = 0; v < kN; ++v) AvH[obase + (size_t)v * kHS3] = f2bf(acc[v]);
}

// ---------------- GRU gating + has_pred select (H bf16 inside AvH) ----------
// gxznh bf16 (M,2048): r=[0,512), z=[512,1024), xn=[1024,1536), hn=[1536,2048)
__global__ __launch_bounds__(256) void gru_kernel(ushort* __restrict__ AvH,
    const ushort* __restrict__ gxznh, const int* __restrict__ hp)
{
    int idx = blockIdx.x * 256 + threadIdx.x;  // < MC*kHS
    int m = idx >> 9;
    int h = idx & 511;
    const ushort* g = gxznh + (size_t)m * 2048;
    float rp = bf2f(g[h]);
    float zp = bf2f(g[h + 512]);
    float xn = bf2f(g[h + 1024]);
    float hv = bf2f(g[h + 1536]);
    float r = 1.f / (1.f + __expf(-rp));
    float z = 1.f / (1.f + __expf(-zp));
    float n = tanhf(xn + r * hv);
    ushort* Hp = AvH + (size_t)m * kHS3 + kHS2 + h;
    float hold = bf2f(*Hp);
    float hnew = (1.f - z) * n + z * hold;
    *Hp = hp[m & 31] ? f2bf(hnew) : f2bf(hold);
}

// ---------------- Hg[b,g] = sum_n sigmoid(G1) * G2 --------------------------
// G12 f32 (M,2048): G1 = cols 0-1023 (incl gate_b), G2 = cols 1024-2047
__global__ __launch_bounds__(256) void hg_kernel(const float* __restrict__ G12,
    float* __restrict__ Hg)
{
    int idx = blockIdx.x * 256 + threadIdx.x;  // < CH*kGS
    int b = idx >> 10, g = idx & 1023;
    size_t base = (size_t)b * kN * 2048 + g;
    float acc = 0.f;
    #pragma unroll 8
    for (int n = 0; n < kN; ++n) {
        float s  = G12[base + (size_t)n * 2048];
        float m2 = G12[base + (size_t)n * 2048 + kGS];
        float sig = 1.f / (1.f + __expf(-s));
        acc = fmaf(sig, m2, acc);
    }
    Hg[idx] = acc;
}

// ---------------- mu/logvar heads -------------------------------------------
__global__ __launch_bounds__(64) void fc_kernel(const float* __restrict__ Hg,
    const float* __restrict__ fc1_w, const float* __restrict__ fc1_b,
    const float* __restrict__ fc2_w, const float* __restrict__ fc2_b,
    float* __restrict__ out, int b0)
{
    __shared__ float hg[kGS];
    int bl = blockIdx.x;
    for (int i = threadIdx.x; i < kGS; i += 64) hg[i] = Hg[(size_t)bl * kGS + i];
    __syncthreads();
    int j = threadIdx.x;
    if (j < kNZ) {
        float s1 = fc1_b[j], s2 = fc2_b[j];
        for (int k = 0; k < kGS; ++k) {
            float h = hg[k];
            s1 = fmaf(h, fc1_w[k * kNZ + j], s1);
            s2 = fmaf(h, fc2_w[k * kNZ + j], s2);
        }
        int bg = b0 + bl;
        out[(size_t)bg * kNZ + j] = s1;
        out[(size_t)kB * kNZ + (size_t)bg * kNZ + j] = s2;
    }
}

}  // namespace

extern "C" void kernel_launch(void* const* d_in, const int* in_sizes, int n_in,
                              void* d_out, int out_size, void* d_ws, size_t ws_size,
                              hipStream_t stream)
{
    const int*   node_types = (const int*)  d_in[0];
    const float* adj        = (const float*)d_in[1];
    const float* finit_w    = (const float*)d_in[2];
    const float* finit_b    = (const float*)d_in[3];
    const float* fe_w       = (const float*)d_in[4];
    const float* fe_b       = (const float*)d_in[5];
    const float* grue_wih   = (const float*)d_in[6];
    const float* grue_whh   = (const float*)d_in[7];
    const float* grue_bih   = (const float*)d_in[8];
    const float* grue_bhh   = (const float*)d_in[9];
    const float* gate_w     = (const float*)d_in[10];
    const float* gate_b     = (const float*)d_in[11];
    const float* mapper_w   = (const float*)d_in[12];
    const float* fc1_w      = (const float*)d_in[13];
    const float* fc1_b      = (const float*)d_in[14];
    const float* fc2_w      = (const float*)d_in[15];
    const float* fc2_b      = (const float*)d_in[16];
    float* out = (float*)d_out;

    // ---- fixed region (float units) ----
    float* W = (float*)d_ws;
    size_t o = 0;
    float*  deg      = W + o; o += (size_t)kB * kN;
    int*    hp       = (int*)(W + o); o += 64;
    float*  biasHS   = W + o; o += 2048;
    float*  biasGXNH = W + o; o += kTE * 2048;
    float*  biasRO   = W + o; o += 2048;
    float*  Hg       = W + o; o += (size_t)kB * kGS;
    ushort* WnsT     = (ushort*)(W + o); o += (size_t)2048 * kHS / 2;
    ushort* catRZNH  = (ushort*)(W + o); o += (size_t)kTE * 2048 * kHS3 / 2;
    ushort* gateMapT = (ushort*)(W + o); o += (size_t)2048 * kHS / 2;
    const size_t fixedFloats = o;

    // per-graph floats: AvH 24576 + HuSt 32768 + gxznh 32768 = 90112
    // (G12 f32 MCx2048 overlays HuSt+gxznh exactly at readout)
    const size_t perGraph = 90112;
    int CH = 512;
    while (CH > 8 &&
           (fixedFloats + (size_t)CH * perGraph) * sizeof(float) > ws_size)
        CH >>= 1;

    // ---- one-time precompute ----
    deg_kernel<<<kB * kN / 256, 256, 0, stream>>>(adj, deg);
    haspred_kernel<<<1, kN, 0, stream>>>(deg, hp);
    biasHS_kernel<<<2048 / 256, 256, 0, stream>>>(fe_w, fe_b, biasHS);
    biasGXNH_kernel<<<kTE * 2048 / 256, 256, 0, stream>>>(grue_bih, grue_bhh, biasGXNH);
    biasRO_kernel<<<2048 / 256, 256, 0, stream>>>(gate_b, biasRO);
    wnst_kernel<<<2048 * kHS / 256, 256, 0, stream>>>(fe_w, WnsT);
    catrznh_kernel<<<dim3(kHS3 / 256, 2048, kTE), 256, 0, stream>>>(grue_wih, grue_whh, catRZNH);
    gatemap_kernel<<<2048 * kHS / 256, 256, 0, stream>>>(gate_w, mapper_w, gateMapT);

    for (int b0 = 0; b0 < kB; b0 += CH) {
        const int MC = CH * kN;  // rows (multiple of 256)
        ushort* AvH   = (ushort*)(W + fixedFloats);        // MC x 1536 bf16
        ushort* HuSt  = AvH   + (size_t)MC * kHS3;         // MC x 2048 bf16
        ushort* gxznh = HuSt  + (size_t)MC * 2048;         // MC x 2048 bf16
        float*  G12   = (float*)HuSt;                      // MC x 2048 f32 (overlay)
        ushort* Hc    = AvH + kHS2;                        // H view, lda 1536

        hinit_kernel<<<MC * kHS / 256, 256, 0, stream>>>(
            node_types + (size_t)b0 * kN, finit_w, finit_b, AvH);

        for (int t = 0; t < kTE; ++t) {
            // HuSt = H @ WnsT^T + [0 | we+fe_b]   (MC x 2048, K=512)
            launch_gemm<ushort>(Hc, kHS3, WnsT, HuSt, biasHS, MC, 2048, kHS, stream);
            // Av -> AvH[:, 0:1024]
            {
                dim3 g(kHS2 / 256, CH);
                av_kernel<<<g, 256, 0, stream>>>(
                    adj + (size_t)b0 * kN * kN, HuSt, deg + (size_t)b0 * kN, AvH);
            }
            // gxznh = [Av|H] @ catRZNH[t]^T + biasGXNH[t]  (MC x 2048, K=1536)
            launch_gemm<ushort>(AvH, kHS3, catRZNH + (size_t)t * 2048 * kHS3, gxznh,
                                biasGXNH + t * 2048, MC, 2048, kHS3, stream);
            // GRU gating (H in place)
            gru_kernel<<<MC * kHS / 256, 256, 0, stream>>>(AvH, gxznh, hp);
        }

        // readout: G12 = H @ [gate|mapper]^T + [gate_b|0]  (MC x 2048, K=512)
        launch_gemm<float>(Hc, kHS3, gateMapT, G12, biasRO, MC, 2048, kHS, stream);
        hg_kernel<<<CH * kGS / 256, 256, 0, stream>>>(G12, Hg);
        fc_kernel<<<CH, 64, 0, stream>>>(Hg, fc1_w, fc1_b, fc2_w, fc2_b, out, b0);
    }
}